// Round 1
// baseline (1113.656 us; speedup 1.0000x reference)
//
#include <hip/hip_runtime.h>
#include <cmath>

// ---------------- CSR build (by dst) ----------------
__global__ void k_hist(const int* __restrict__ dst, int* __restrict__ counts, int E) {
  int e = blockIdx.x * blockDim.x + threadIdx.x;
  if (e < E) atomicAdd(&counts[dst[e]], 1);
}

__global__ void k_scan(const int* __restrict__ counts, int* __restrict__ indptr, int n) {
  __shared__ int buf[1024];
  __shared__ int base;
  int tid = threadIdx.x;
  if (tid == 0) { base = 0; indptr[0] = 0; }
  __syncthreads();
  int nchunks = (n + 1023) / 1024;
  for (int c = 0; c < nchunks; ++c) {
    int i = c * 1024 + tid;
    int v = (i < n) ? counts[i] : 0;
    buf[tid] = v;
    __syncthreads();
    for (int off = 1; off < 1024; off <<= 1) {
      int t = (tid >= off) ? buf[tid - off] : 0;
      __syncthreads();
      buf[tid] += t;
      __syncthreads();
    }
    int total = buf[1023];
    if (i < n) indptr[i + 1] = base + buf[tid];
    __syncthreads();
    if (tid == 0) base += total;
    __syncthreads();
  }
}

__global__ void k_scatter(const int* __restrict__ dst, const int* __restrict__ indptr,
                          int* __restrict__ cursor, int* __restrict__ ecsr, int E) {
  int e = blockIdx.x * blockDim.x + threadIdx.x;
  if (e < E) {
    int d = dst[e];
    int pos = indptr[d] + atomicAdd(&cursor[d], 1);
    ecsr[pos] = e;
  }
}

// deterministic edge order within each bucket (matches np segment op order,
// and makes fp32 sums identical across graph replays)
__global__ void k_sortbuckets(const int* __restrict__ indptr, int* __restrict__ ecsr, int N) {
  int n = blockIdx.x * blockDim.x + threadIdx.x;
  if (n >= N) return;
  int s = indptr[n], t = indptr[n + 1];
  for (int i = s + 1; i < t; ++i) {
    int key = ecsr[i];
    int j = i - 1;
    while (j >= s && ecsr[j] > key) { ecsr[j + 1] = ecsr[j]; --j; }
    ecsr[j + 1] = key;
  }
}

// ---------------- GEMMs (double accumulation for accuracy) ----------------
// f0[N,256] = x[N,128] @ W0[128,256]; block = 256 cols, 8 rows per block
__global__ void k_gemm0(const float* __restrict__ x, const float* __restrict__ W0,
                        float* __restrict__ f0, int N) {
  int col = threadIdx.x;
  int row0 = blockIdx.x * 8;
  const float* xr[8];
#pragma unroll
  for (int r = 0; r < 8; ++r) {
    int row = row0 + r; if (row >= N) row = N - 1;
    xr[r] = x + (size_t)row * 128;
  }
  double acc[8] = {};
  for (int k = 0; k < 128; ++k) {
    double w = (double)W0[k * 256 + col];
#pragma unroll
    for (int r = 0; r < 8; ++r) acc[r] += (double)xr[r][k] * w;
  }
#pragma unroll
  for (int r = 0; r < 8; ++r) {
    int row = row0 + r;
    if (row < N) f0[(size_t)row * 256 + col] = (float)acc[r];
  }
}

// f1[N,32] = h[N,256] @ W1[256,32]; block = 8 rows x 32 cols
__global__ void k_gemm1(const float* __restrict__ h, const float* __restrict__ W1,
                        float* __restrict__ f1, int N) {
  int t = threadIdx.x;
  int r = t >> 5, col = t & 31;
  int row = blockIdx.x * 8 + r;
  int rr = row < N ? row : N - 1;
  const float* hr = h + (size_t)rr * 256;
  double acc = 0;
  for (int k = 0; k < 256; ++k)
    acc += (double)hr[k] * (double)W1[k * 32 + col];
  if (row < N) f1[(size_t)row * 32 + col] = (float)acc;
}

// ---------------- attention dots ----------------
// layer0: el[n,h] = sum_d f0[n,h*32+d]*al0[h,d]  (block = one node, 256 thr)
__global__ void k_elr0(const float* __restrict__ f0, const float* __restrict__ al,
                       const float* __restrict__ ar, float* __restrict__ el,
                       float* __restrict__ er, int N) {
  int n = blockIdx.x;
  int t = threadIdx.x;
  float v = f0[(size_t)n * 256 + t];
  double pl = (double)v * (double)al[t];
  double pr = (double)v * (double)ar[t];
#pragma unroll
  for (int off = 16; off >= 1; off >>= 1) {
    pl += __shfl_xor(pl, off, 64);
    pr += __shfl_xor(pr, off, 64);
  }
  if ((t & 31) == 0) {
    int h = t >> 5;
    el[n * 8 + h] = (float)pl;
    er[n * 8 + h] = (float)pr;
  }
}

// layer1 (H=1): block = 8 nodes x 32 lanes
__global__ void k_elr1(const float* __restrict__ f1, const float* __restrict__ al,
                       const float* __restrict__ ar, float* __restrict__ el,
                       float* __restrict__ er, int N) {
  int t = threadIdx.x;
  int grp = t >> 5, d = t & 31;
  int n = blockIdx.x * 8 + grp;
  int nn = n < N ? n : N - 1;
  float v = f1[(size_t)nn * 32 + d];
  double pl = (double)v * (double)al[d];
  double pr = (double)v * (double)ar[d];
#pragma unroll
  for (int off = 16; off >= 1; off >>= 1) {
    pl += __shfl_xor(pl, off, 64);
    pr += __shfl_xor(pr, off, 64);
  }
  if (d == 0 && n < N) { el[n] = (float)pl; er[n] = (float)pr; }
}

// ---------------- edge scores + segment softmax ----------------
template <int H>
__global__ void k_escore(const int* __restrict__ src, const int* __restrict__ dst,
                         const float* __restrict__ el, const float* __restrict__ er,
                         float* __restrict__ esc, int E) {
  long idx = (long)blockIdx.x * blockDim.x + threadIdx.x;
  if (idx >= (long)E * H) return;
  int e = (int)(idx / H), h = (int)(idx % H);
  float v = el[src[e] * H + h] + er[dst[e] * H + h];
  esc[idx] = v >= 0.f ? v : 0.2f * v;   // leaky_relu(0.2)
}

template <int H>
__global__ void k_softmax(float* __restrict__ esc, const int* __restrict__ indptr,
                          const int* __restrict__ ecsr, int N) {
  long idx = (long)blockIdx.x * blockDim.x + threadIdx.x;
  if (idx >= (long)N * H) return;
  int n = (int)(idx / H), h = (int)(idx % H);
  int s = indptr[n], t = indptr[n + 1];
  float m = -INFINITY;
  for (int i = s; i < t; ++i) m = fmaxf(m, esc[(size_t)ecsr[i] * H + h]);
  float sum = 0.f;
  for (int i = s; i < t; ++i) {
    size_t p = (size_t)ecsr[i] * H + h;
    float a = expf(esc[p] - m);
    esc[p] = a;
    sum += a;
  }
  for (int i = s; i < t; ++i) {
    size_t p = (size_t)ecsr[i] * H + h;
    esc[p] = esc[p] / sum;   // division (not rcp-mul) to match reference
  }
}

// ---------------- weighted aggregation ----------------
// layer0: block = one dst node, 256 thr = (h,d); epilogue: +b0, ELU
__global__ void k_agg0(const float* __restrict__ esc, const float* __restrict__ f0,
                       const int* __restrict__ indptr, const int* __restrict__ ecsr,
                       const int* __restrict__ src, const float* __restrict__ b0,
                       float* __restrict__ hout, int N) {
  int n = blockIdx.x;
  int t = threadIdx.x;
  int h = t >> 5;
  int s = indptr[n], e_ = indptr[n + 1];
  float acc = 0.f;
  for (int i = s; i < e_; ++i) {
    int e = ecsr[i];
    int sn = src[e];
    acc += esc[(size_t)e * 8 + h] * f0[(size_t)sn * 256 + t];
  }
  float o = acc + b0[t];
  hout[(size_t)n * 256 + t] = o > 0.f ? o : expm1f(o);   // jax.nn.elu
}

// layer1 (H=1): block = 8 nodes x 32 lanes; +b1 (mean over 1 head = identity)
__global__ void k_agg1(const float* __restrict__ esc, const float* __restrict__ f1,
                       const int* __restrict__ indptr, const int* __restrict__ ecsr,
                       const int* __restrict__ src, const float* __restrict__ b1,
                       float* __restrict__ h1, int N) {
  int t = threadIdx.x;
  int grp = t >> 5, d = t & 31;
  int n = blockIdx.x * 8 + grp;
  if (n >= N) return;
  int s = indptr[n], e_ = indptr[n + 1];
  float acc = 0.f;
  for (int i = s; i < e_; ++i) {
    int e = ecsr[i];
    acc += esc[e] * f1[(size_t)src[e] * 32 + d];
  }
  h1[(size_t)n * 32 + d] = acc + b1[d];
}

// ---------------- predictor ----------------
// block = 8 samples x 32 lanes; matvecs via shfl broadcast, double acc
__global__ void k_pred(const float* __restrict__ h1, const float* __restrict__ P1,
                       const float* __restrict__ pb1, const float* __restrict__ P2,
                       const float* __restrict__ pb2, const float* __restrict__ P3,
                       const float* __restrict__ pb3, float* __restrict__ out,
                       int num_edge, int total) {
  int t = threadIdx.x;
  int lane = t & 31, grp = t >> 5;
  int k = blockIdx.x * 8 + grp;
  int kk = k < total ? k : 0;
  float z;
  if (kk < num_edge) {
    z = h1[(size_t)kk * 32 + lane] * h1[(size_t)(kk + num_edge) * 32 + lane];
  } else {
    int i = kk - num_edge;
    z = h1[(size_t)(i % num_edge) * 32 + lane] * h1[(size_t)(2 * num_edge + i) * 32 + lane];
  }
  double a1 = 0;
#pragma unroll
  for (int d = 0; d < 32; ++d)
    a1 += (double)__shfl(z, d, 32) * (double)P1[d * 32 + lane];
  float t1 = (float)(a1 + (double)pb1[lane]);
  t1 = t1 > 0.f ? t1 : 0.f;
  double a2 = 0;
#pragma unroll
  for (int d = 0; d < 32; ++d)
    a2 += (double)__shfl(t1, d, 32) * (double)P2[d * 32 + lane];
  float t2 = (float)(a2 + (double)pb2[lane]);
  t2 = t2 > 0.f ? t2 : 0.f;
  double a3 = (double)t2 * (double)P3[lane];
#pragma unroll
  for (int off = 16; off >= 1; off >>= 1) a3 += __shfl_xor(a3, off, 64);
  if (lane == 0 && k < total) out[k] = (float)(a3 + (double)pb3[0]);
}

extern "C" void kernel_launch(void* const* d_in, const int* in_sizes, int n_in,
                              void* d_out, int out_size, void* d_ws, size_t ws_size,
                              hipStream_t stream) {
  const float* x   = (const float*)d_in[0];
  const int*   src = (const int*)d_in[1];
  const int*   dst = (const int*)d_in[2];
  // d_in[3] = neg_sample_ratio (derived from sizes instead: no device read needed)
  const float* W0  = (const float*)d_in[4];
  const float* al0 = (const float*)d_in[5];
  const float* ar0 = (const float*)d_in[6];
  const float* b0  = (const float*)d_in[7];
  const float* W1  = (const float*)d_in[8];
  const float* al1 = (const float*)d_in[9];
  const float* ar1 = (const float*)d_in[10];
  const float* b1  = (const float*)d_in[11];
  const float* P1  = (const float*)d_in[12];
  const float* pb1 = (const float*)d_in[13];
  const float* P2  = (const float*)d_in[14];
  const float* pb2 = (const float*)d_in[15];
  const float* P3  = (const float*)d_in[16];
  const float* pb3 = (const float*)d_in[17];

  int N = in_sizes[0] / 128;
  int E = in_sizes[1];
  int num_edge = N - out_size;   // N=(2+r)*ne, out=(1+r)*ne -> ne = N-out

  size_t off = 0;
  auto alloc = [&](size_t bytes) -> void* {
    void* p = (char*)d_ws + off;
    off += (bytes + 255) & ~(size_t)255;
    return p;
  };
  float* f0     = (float*)alloc((size_t)N * 256 * 4);
  float* hbuf   = (float*)alloc((size_t)N * 256 * 4);
  float* esc    = (float*)alloc((size_t)E * 8 * 4);
  float* el     = (float*)alloc((size_t)N * 8 * 4);
  float* er     = (float*)alloc((size_t)N * 8 * 4);
  int*   indptr = (int*)alloc((size_t)(N + 1) * 4);
  int*   ecsr   = (int*)alloc((size_t)E * 4);
  int*   counts = (int*)alloc((size_t)N * 4);
  int*   cursor = (int*)alloc((size_t)N * 4);
  if (off > ws_size) return;  // diagnosable: output stays zero
  // aliases: lifetimes disjoint
  float* f1   = f0;                     // f0 dead after k_agg0
  float* h1   = f0 + (size_t)N * 32;    // next to f1, both fit in f0 region
  float* esc1 = esc;                    // layer0 scores dead after k_agg0
  float* el1  = el;
  float* er1  = er;

  hipMemsetAsync(counts, 0, (size_t)N * 4, stream);
  hipMemsetAsync(cursor, 0, (size_t)N * 4, stream);
  int gE = (E + 255) / 256;
  k_hist<<<gE, 256, 0, stream>>>(dst, counts, E);
  k_scan<<<1, 1024, 0, stream>>>(counts, indptr, N);
  k_scatter<<<gE, 256, 0, stream>>>(dst, indptr, cursor, ecsr, E);
  k_sortbuckets<<<(N + 255) / 256, 256, 0, stream>>>(indptr, ecsr, N);

  k_gemm0<<<(N + 7) / 8, 256, 0, stream>>>(x, W0, f0, N);
  k_elr0<<<N, 256, 0, stream>>>(f0, al0, ar0, el, er, N);
  k_escore<8><<<(int)(((long)E * 8 + 255) / 256), 256, 0, stream>>>(src, dst, el, er, esc, E);
  k_softmax<8><<<(int)(((long)N * 8 + 255) / 256), 256, 0, stream>>>(esc, indptr, ecsr, N);
  k_agg0<<<N, 256, 0, stream>>>(esc, f0, indptr, ecsr, src, b0, hbuf, N);

  k_gemm1<<<(N + 7) / 8, 256, 0, stream>>>(hbuf, W1, f1, N);
  k_elr1<<<(N + 7) / 8, 256, 0, stream>>>(f1, al1, ar1, el1, er1, N);
  k_escore<1><<<gE, 256, 0, stream>>>(src, dst, el1, er1, esc1, E);
  k_softmax<1><<<(N + 255) / 256, 256, 0, stream>>>(esc1, indptr, ecsr, N);
  k_agg1<<<(N + 7) / 8, 256, 0, stream>>>(esc1, f1, indptr, ecsr, src, b1, h1, N);

  k_pred<<<(out_size + 7) / 8, 256, 0, stream>>>(h1, P1, pb1, P2, pb2, P3, pb3,
                                                 (float*)d_out, num_edge, out_size);
}

// Round 2
// 669.659 us; speedup vs baseline: 1.6630x; 1.6630x over previous
//
#include <hip/hip_runtime.h>
#include <cmath>

#ifndef CAP0
#define CAP0 192   // max staged degree; Poisson(16) max ~40, huge margin. Fallback path covers >CAP.
#endif

// ---------------- CSR build (by dst) ----------------
__global__ void k_hist(const int* __restrict__ dst, int* __restrict__ counts, int E) {
  int e = blockIdx.x * blockDim.x + threadIdx.x;
  if (e < E) atomicAdd(&counts[dst[e]], 1);
}

// inclusive scan within 256-blocks
__global__ void k_blockscan(const int* __restrict__ counts, int* __restrict__ partial,
                            int* __restrict__ bsums, int n) {
  __shared__ int buf[256];
  int tid = threadIdx.x;
  int i = blockIdx.x * 256 + tid;
  int v = (i < n) ? counts[i] : 0;
  buf[tid] = v;
  __syncthreads();
  for (int off = 1; off < 256; off <<= 1) {
    int t = (tid >= off) ? buf[tid - off] : 0;
    __syncthreads();
    buf[tid] += t;
    __syncthreads();
  }
  if (i < n) partial[i] = buf[tid];
  if (tid == 255) bsums[blockIdx.x] = buf[255];
}

// exclusive scan of block sums (nb <= 256), in place
__global__ void k_scansums(int* __restrict__ bsums, int nb) {
  __shared__ int buf[256];
  int tid = threadIdx.x;
  int v = (tid < nb) ? bsums[tid] : 0;
  buf[tid] = v;
  __syncthreads();
  for (int off = 1; off < 256; off <<= 1) {
    int t = (tid >= off) ? buf[tid - off] : 0;
    __syncthreads();
    buf[tid] += t;
    __syncthreads();
  }
  if (tid < nb) bsums[tid] = buf[tid] - v;
}

__global__ void k_addoff(const int* __restrict__ partial, const int* __restrict__ bsums,
                         int* __restrict__ indptr, int n) {
  int i = blockIdx.x * blockDim.x + threadIdx.x;
  if (i == 0) indptr[0] = 0;
  if (i < n) indptr[i + 1] = partial[i] + bsums[i >> 8];
}

__global__ void k_scatter(const int* __restrict__ dst, const int* __restrict__ indptr,
                          int* __restrict__ cursor, int* __restrict__ ecsr, int E) {
  int e = blockIdx.x * blockDim.x + threadIdx.x;
  if (e < E) {
    int d = dst[e];
    int pos = indptr[d] + atomicAdd(&cursor[d], 1);
    ecsr[pos] = e;
  }
}

// deterministic edge-ascending order inside each bucket (matches np segment order)
__global__ void k_sortbuckets(const int* __restrict__ indptr, int* __restrict__ ecsr, int N) {
  int n = blockIdx.x * blockDim.x + threadIdx.x;
  if (n >= N) return;
  int s = indptr[n], t = indptr[n + 1];
  for (int i = s + 1; i < t; ++i) {
    int key = ecsr[i];
    int j = i - 1;
    while (j >= s && ecsr[j] > key) { ecsr[j + 1] = ecsr[j]; --j; }
    ecsr[j + 1] = key;
  }
}

// ---------------- GEMM0 + fused attention dots (layer 0) ----------------
// f0[N,256] = x[N,128] @ W0[128,256], fp64 acc; epilogue: el/er per (row, head)
__global__ void k_gemm0(const float* __restrict__ x, const float* __restrict__ W0,
                        const float* __restrict__ al, const float* __restrict__ ar,
                        float* __restrict__ f0, float* __restrict__ el,
                        float* __restrict__ er, int N) {
  int col = threadIdx.x;            // 0..255 == h*32+d
  int row0 = blockIdx.x * 8;
  const float* xr[8];
#pragma unroll
  for (int r = 0; r < 8; ++r) {
    int row = row0 + r; if (row >= N) row = N - 1;
    xr[r] = x + (size_t)row * 128;
  }
  double acc[8] = {};
  for (int k = 0; k < 128; ++k) {
    double w = (double)W0[k * 256 + col];
#pragma unroll
    for (int r = 0; r < 8; ++r) acc[r] += (double)xr[r][k] * w;
  }
  int h = col >> 5;
  double a_l = (double)al[col], a_r = (double)ar[col];
#pragma unroll
  for (int r = 0; r < 8; ++r) {
    int row = row0 + r;
    if (row < N) f0[(size_t)row * 256 + col] = (float)acc[r];
    double pl = acc[r] * a_l;
    double pr = acc[r] * a_r;
#pragma unroll
    for (int off = 16; off >= 1; off >>= 1) {
      pl += __shfl_xor(pl, off, 32);
      pr += __shfl_xor(pr, off, 32);
    }
    if ((col & 31) == 0 && row < N) {
      el[row * 8 + h] = (float)pl;
      er[row * 8 + h] = (float)pr;
    }
  }
}

// ---------------- fused edge kernel layer 0 ----------------
// one block = one dst node; 256 thr = (h = t>>5, lane = t&31)
// score -> segment softmax (LDS) -> weighted gather-sum of f0 -> +b0 -> ELU
__global__ void k_fused0(const float* __restrict__ el, const float* __restrict__ er,
                         const float* __restrict__ f0, const int* __restrict__ indptr,
                         const int* __restrict__ ecsr, const int* __restrict__ src,
                         const float* __restrict__ b0, float* __restrict__ hout, int N) {
  __shared__ float s_w[CAP0 * 8];
  __shared__ int s_src[CAP0];
  int n = blockIdx.x;
  int t = threadIdx.x;
  int h = t >> 5, lane = t & 31;
  int s = indptr[n], e_ = indptr[n + 1];
  int deg = e_ - s;
  float er_h = er[n * 8 + h];
  float acc = 0.f;
  if (deg <= CAP0) {
    float m = -INFINITY;
    for (int i = lane; i < deg; i += 32) {
      int e = ecsr[s + i];
      int sn = src[e];
      if (h == 0) s_src[i] = sn;
      float v = el[sn * 8 + h] + er_h;
      v = v >= 0.f ? v : 0.2f * v;
      s_w[i * 8 + h] = v;
      m = fmaxf(m, v);
    }
#pragma unroll
    for (int off = 16; off >= 1; off >>= 1) m = fmaxf(m, __shfl_xor(m, off, 32));
    float sum = 0.f;
    for (int i = lane; i < deg; i += 32) {
      float a = expf(s_w[i * 8 + h] - m);
      s_w[i * 8 + h] = a;
      sum += a;
    }
#pragma unroll
    for (int off = 16; off >= 1; off >>= 1) sum += __shfl_xor(sum, off, 32);
    for (int i = lane; i < deg; i += 32) s_w[i * 8 + h] /= sum;   // IEEE div as reference
    __syncthreads();
    int i = 0;
    for (; i + 4 <= deg; i += 4) {
      float a0 = s_w[(i + 0) * 8 + h], a1 = s_w[(i + 1) * 8 + h];
      float a2 = s_w[(i + 2) * 8 + h], a3 = s_w[(i + 3) * 8 + h];
      int n0 = s_src[i + 0], n1 = s_src[i + 1], n2 = s_src[i + 2], n3 = s_src[i + 3];
      float v0 = f0[(size_t)n0 * 256 + t];
      float v1 = f0[(size_t)n1 * 256 + t];
      float v2 = f0[(size_t)n2 * 256 + t];
      float v3 = f0[(size_t)n3 * 256 + t];
      acc += a0 * v0; acc += a1 * v1; acc += a2 * v2; acc += a3 * v3;
    }
    for (; i < deg; ++i) acc += s_w[i * 8 + h] * f0[(size_t)s_src[i] * 256 + t];
  } else {
    // 3-pass recompute fallback (no LDS capacity) — block-uniform branch
    float m = -INFINITY;
    for (int i = lane; i < deg; i += 32) {
      float v = el[src[ecsr[s + i]] * 8 + h] + er_h;
      v = v >= 0.f ? v : 0.2f * v;
      m = fmaxf(m, v);
    }
#pragma unroll
    for (int off = 16; off >= 1; off >>= 1) m = fmaxf(m, __shfl_xor(m, off, 32));
    float sum = 0.f;
    for (int i = lane; i < deg; i += 32) {
      float v = el[src[ecsr[s + i]] * 8 + h] + er_h;
      v = v >= 0.f ? v : 0.2f * v;
      sum += expf(v - m);
    }
#pragma unroll
    for (int off = 16; off >= 1; off >>= 1) sum += __shfl_xor(sum, off, 32);
    for (int i = 0; i < deg; ++i) {
      int sn = src[ecsr[s + i]];
      float v = el[sn * 8 + h] + er_h;
      v = v >= 0.f ? v : 0.2f * v;
      float a = expf(v - m) / sum;
      acc += a * f0[(size_t)sn * 256 + t];
    }
  }
  float o = acc + b0[t];
  hout[(size_t)n * 256 + t] = o > 0.f ? o : expm1f(o);   // jax.nn.elu
}

// ---------------- GEMM1 + fused attention dots (layer 1, H=1) ----------------
// f1[N,32] = h[N,256] @ W1[256,32]; block = 8 rows x 32 cols
__global__ void k_gemm1(const float* __restrict__ h, const float* __restrict__ W1,
                        const float* __restrict__ al, const float* __restrict__ ar,
                        float* __restrict__ f1, float* __restrict__ el,
                        float* __restrict__ er, int N) {
  int t = threadIdx.x;
  int r = t >> 5, col = t & 31;
  int row = blockIdx.x * 8 + r;
  int rr = row < N ? row : N - 1;
  const float* hr = h + (size_t)rr * 256;
  double acc = 0;
  for (int k = 0; k < 256; ++k)
    acc += (double)hr[k] * (double)W1[k * 32 + col];
  float f = (float)acc;
  double pl = (double)f * (double)al[col];
  double pr = (double)f * (double)ar[col];
#pragma unroll
  for (int off = 16; off >= 1; off >>= 1) {
    pl += __shfl_xor(pl, off, 32);
    pr += __shfl_xor(pr, off, 32);
  }
  if (row < N) {
    f1[(size_t)row * 32 + col] = f;
    if (col == 0) { el[row] = (float)pl; er[row] = (float)pr; }
  }
}

// ---------------- fused edge kernel layer 1 (H=1, D=32) ----------------
// block = 256 = 4 nodes x 64 lanes (one wave per node; no __syncthreads -> safe w/ divergent deg)
__global__ void k_fused1(const float* __restrict__ el, const float* __restrict__ er,
                         const float* __restrict__ f1, const int* __restrict__ indptr,
                         const int* __restrict__ ecsr, const int* __restrict__ src,
                         const float* __restrict__ b1, float* __restrict__ h1, int N) {
  __shared__ float s_w[4][CAP0];
  __shared__ int s_s[4][CAP0];
  int g = threadIdx.x >> 6;
  int lane = threadIdx.x & 63;
  int n = blockIdx.x * 4 + g;
  int nn = n < N ? n : N - 1;
  int s = indptr[nn], e_ = indptr[nn + 1];
  int deg = e_ - s;
  float er_n = er[nn];
  float acc = 0.f;
  int d = lane & 31;
  if (deg <= CAP0) {
    float m = -INFINITY;
    for (int i = lane; i < deg; i += 64) {
      int e = ecsr[s + i];
      int sn = src[e];
      s_s[g][i] = sn;
      float v = el[sn] + er_n;
      v = v >= 0.f ? v : 0.2f * v;
      s_w[g][i] = v;
      m = fmaxf(m, v);
    }
#pragma unroll
    for (int off = 32; off >= 1; off >>= 1) m = fmaxf(m, __shfl_xor(m, off, 64));
    float sum = 0.f;
    for (int i = lane; i < deg; i += 64) {
      float a = expf(s_w[g][i] - m);
      s_w[g][i] = a;
      sum += a;
    }
#pragma unroll
    for (int off = 32; off >= 1; off >>= 1) sum += __shfl_xor(sum, off, 64);
    for (int i = lane; i < deg; i += 64) s_w[g][i] /= sum;
    // aggregation: lanes 0..31 (dims), sequential edge order (wave-synchronous LDS: in-order per wave)
    if (lane < 32) {
      int i = 0;
      for (; i + 4 <= deg; i += 4) {
        float a0 = s_w[g][i + 0], a1 = s_w[g][i + 1], a2 = s_w[g][i + 2], a3 = s_w[g][i + 3];
        int n0 = s_s[g][i + 0], n1 = s_s[g][i + 1], n2 = s_s[g][i + 2], n3 = s_s[g][i + 3];
        float v0 = f1[(size_t)n0 * 32 + d];
        float v1 = f1[(size_t)n1 * 32 + d];
        float v2 = f1[(size_t)n2 * 32 + d];
        float v3 = f1[(size_t)n3 * 32 + d];
        acc += a0 * v0; acc += a1 * v1; acc += a2 * v2; acc += a3 * v3;
      }
      for (; i < deg; ++i) acc += s_w[g][i] * f1[(size_t)s_s[g][i] * 32 + d];
    }
  } else {
    float m = -INFINITY;
    for (int i = lane; i < deg; i += 64) {
      float v = el[src[ecsr[s + i]]] + er_n;
      v = v >= 0.f ? v : 0.2f * v;
      m = fmaxf(m, v);
    }
#pragma unroll
    for (int off = 32; off >= 1; off >>= 1) m = fmaxf(m, __shfl_xor(m, off, 64));
    float sum = 0.f;
    for (int i = lane; i < deg; i += 64) {
      float v = el[src[ecsr[s + i]]] + er_n;
      v = v >= 0.f ? v : 0.2f * v;
      sum += expf(v - m);
    }
#pragma unroll
    for (int off = 32; off >= 1; off >>= 1) sum += __shfl_xor(sum, off, 64);
    if (lane < 32) {
      for (int i = 0; i < deg; ++i) {
        int sn = src[ecsr[s + i]];
        float v = el[sn] + er_n;
        v = v >= 0.f ? v : 0.2f * v;
        float a = expf(v - m) / sum;
        acc += a * f1[(size_t)sn * 32 + d];
      }
    }
  }
  if (lane < 32 && n < N) h1[(size_t)n * 32 + d] = acc + b1[d];
}

// ---------------- predictor ----------------
__global__ void k_pred(const float* __restrict__ h1, const float* __restrict__ P1,
                       const float* __restrict__ pb1, const float* __restrict__ P2,
                       const float* __restrict__ pb2, const float* __restrict__ P3,
                       const float* __restrict__ pb3, float* __restrict__ out,
                       int num_edge, int total) {
  int t = threadIdx.x;
  int lane = t & 31, grp = t >> 5;
  int k = blockIdx.x * 8 + grp;
  int kk = k < total ? k : 0;
  float z;
  if (kk < num_edge) {
    z = h1[(size_t)kk * 32 + lane] * h1[(size_t)(kk + num_edge) * 32 + lane];
  } else {
    int i = kk - num_edge;
    z = h1[(size_t)(i % num_edge) * 32 + lane] * h1[(size_t)(2 * num_edge + i) * 32 + lane];
  }
  double a1 = 0;
#pragma unroll
  for (int d = 0; d < 32; ++d)
    a1 += (double)__shfl(z, d, 32) * (double)P1[d * 32 + lane];
  float t1 = (float)(a1 + (double)pb1[lane]);
  t1 = t1 > 0.f ? t1 : 0.f;
  double a2 = 0;
#pragma unroll
  for (int d = 0; d < 32; ++d)
    a2 += (double)__shfl(t1, d, 32) * (double)P2[d * 32 + lane];
  float t2 = (float)(a2 + (double)pb2[lane]);
  t2 = t2 > 0.f ? t2 : 0.f;
  double a3 = (double)t2 * (double)P3[lane];
#pragma unroll
  for (int off = 16; off >= 1; off >>= 1) a3 += __shfl_xor(a3, off, 64);
  if (lane == 0 && k < total) out[k] = (float)(a3 + (double)pb3[0]);
}

extern "C" void kernel_launch(void* const* d_in, const int* in_sizes, int n_in,
                              void* d_out, int out_size, void* d_ws, size_t ws_size,
                              hipStream_t stream) {
  const float* x   = (const float*)d_in[0];
  const int*   src = (const int*)d_in[1];
  const int*   dst = (const int*)d_in[2];
  const float* W0  = (const float*)d_in[4];
  const float* al0 = (const float*)d_in[5];
  const float* ar0 = (const float*)d_in[6];
  const float* b0  = (const float*)d_in[7];
  const float* W1  = (const float*)d_in[8];
  const float* al1 = (const float*)d_in[9];
  const float* ar1 = (const float*)d_in[10];
  const float* b1  = (const float*)d_in[11];
  const float* P1  = (const float*)d_in[12];
  const float* pb1 = (const float*)d_in[13];
  const float* P2  = (const float*)d_in[14];
  const float* pb2 = (const float*)d_in[15];
  const float* P3  = (const float*)d_in[16];
  const float* pb3 = (const float*)d_in[17];

  int N = in_sizes[0] / 128;
  int E = in_sizes[1];
  int num_edge = N - out_size;   // N=(2+r)*ne, out=(1+r)*ne

  size_t off = 0;
  auto alloc = [&](size_t bytes) -> void* {
    void* p = (char*)d_ws + off;
    off += (bytes + 255) & ~(size_t)255;
    return p;
  };
  float* f0     = (float*)alloc((size_t)N * 256 * 4);
  float* hbuf   = (float*)alloc((size_t)N * 256 * 4);
  float* el     = (float*)alloc((size_t)N * 8 * 4);
  float* er     = (float*)alloc((size_t)N * 8 * 4);
  int*   indptr = (int*)alloc((size_t)(N + 1) * 4);
  int*   ecsr   = (int*)alloc((size_t)E * 4);
  int*   counts = (int*)alloc((size_t)N * 4);
  int*   cursor = (int*)alloc((size_t)N * 4);
  int*   partial= (int*)alloc((size_t)N * 4);
  int*   bsums  = (int*)alloc(256 * 4);
  if (off > ws_size) return;
  // aliases (disjoint lifetimes)
  float* f1  = f0;                   // f0 dead after k_fused0
  float* h1  = f0 + (size_t)N * 32;
  float* el1 = el;                   // layer0 el/er dead after k_fused0
  float* er1 = er;

  int gE = (E + 255) / 256;
  int gN = (N + 255) / 256;          // 196 blocks
  hipMemsetAsync(counts, 0, (size_t)N * 4, stream);
  hipMemsetAsync(cursor, 0, (size_t)N * 4, stream);
  k_hist<<<gE, 256, 0, stream>>>(dst, counts, E);
  k_blockscan<<<gN, 256, 0, stream>>>(counts, partial, bsums, N);
  k_scansums<<<1, 256, 0, stream>>>(bsums, gN);
  k_addoff<<<gN, 256, 0, stream>>>(partial, bsums, indptr, N);
  k_scatter<<<gE, 256, 0, stream>>>(dst, indptr, cursor, ecsr, E);
  k_sortbuckets<<<gN, 256, 0, stream>>>(indptr, ecsr, N);

  k_gemm0<<<(N + 7) / 8, 256, 0, stream>>>(x, W0, al0, ar0, f0, el, er, N);
  k_fused0<<<N, 256, 0, stream>>>(el, er, f0, indptr, ecsr, src, b0, hbuf, N);

  k_gemm1<<<(N + 7) / 8, 256, 0, stream>>>(hbuf, W1, al1, ar1, f1, el1, er1, N);
  k_fused1<<<(N + 3) / 4, 256, 0, stream>>>(el1, er1, f1, indptr, ecsr, src, b1, h1, N);

  k_pred<<<(out_size + 7) / 8, 256, 0, stream>>>(h1, P1, pb1, P2, pb2, P3, pb3,
                                                 (float*)d_out, num_edge, out_size);
}

// Round 3
// 600.961 us; speedup vs baseline: 1.8531x; 1.1143x over previous
//
#include <hip/hip_runtime.h>
#include <cmath>

#ifndef CAP0
#define CAP0 192   // max staged degree; Poisson(16) max ~40, huge margin. Fallback path covers >CAP.
#endif

// ---------------- CSR build (by dst) ----------------
__global__ void k_hist(const int* __restrict__ dst, int* __restrict__ counts, int E) {
  int e = blockIdx.x * blockDim.x + threadIdx.x;
  if (e < E) atomicAdd(&counts[dst[e]], 1);
}

// inclusive scan within 256-blocks
__global__ void k_blockscan(const int* __restrict__ counts, int* __restrict__ partial,
                            int* __restrict__ bsums, int n) {
  __shared__ int buf[256];
  int tid = threadIdx.x;
  int i = blockIdx.x * 256 + tid;
  int v = (i < n) ? counts[i] : 0;
  buf[tid] = v;
  __syncthreads();
  for (int off = 1; off < 256; off <<= 1) {
    int t = (tid >= off) ? buf[tid - off] : 0;
    __syncthreads();
    buf[tid] += t;
    __syncthreads();
  }
  if (i < n) partial[i] = buf[tid];
  if (tid == 255) bsums[blockIdx.x] = buf[255];
}

// exclusive scan of block sums (nb <= 256), in place
__global__ void k_scansums(int* __restrict__ bsums, int nb) {
  __shared__ int buf[256];
  int tid = threadIdx.x;
  int v = (tid < nb) ? bsums[tid] : 0;
  buf[tid] = v;
  __syncthreads();
  for (int off = 1; off < 256; off <<= 1) {
    int t = (tid >= off) ? buf[tid - off] : 0;
    __syncthreads();
    buf[tid] += t;
    __syncthreads();
  }
  if (tid < nb) bsums[tid] = buf[tid] - v;
}

__global__ void k_addoff(const int* __restrict__ partial, const int* __restrict__ bsums,
                         int* __restrict__ indptr, int n) {
  int i = blockIdx.x * blockDim.x + threadIdx.x;
  if (i == 0) indptr[0] = 0;
  if (i < n) indptr[i + 1] = partial[i] + bsums[i >> 8];
}

__global__ void k_scatter(const int* __restrict__ dst, const int* __restrict__ indptr,
                          int* __restrict__ cursor, int* __restrict__ ecsr, int E) {
  int e = blockIdx.x * blockDim.x + threadIdx.x;
  if (e < E) {
    int d = dst[e];
    int pos = indptr[d] + atomicAdd(&cursor[d], 1);
    ecsr[pos] = e;
  }
}

// deterministic edge-ascending order inside each bucket (matches np segment order)
__global__ void k_sortbuckets(const int* __restrict__ indptr, int* __restrict__ ecsr, int N) {
  int n = blockIdx.x * blockDim.x + threadIdx.x;
  if (n >= N) return;
  int s = indptr[n], t = indptr[n + 1];
  for (int i = s + 1; i < t; ++i) {
    int key = ecsr[i];
    int j = i - 1;
    while (j >= s && ecsr[j] > key) { ecsr[j + 1] = ecsr[j]; --j; }
    ecsr[j + 1] = key;
  }
}

// ---------------- GEMM0 + fused attention dots (layer 0) ----------------
// f0[N,256] = x[N,128] @ W0[128,256], fp32 4-chunk blocked acc (accuracy + ILP)
// epilogue: el/er per (row, head)
__global__ void k_gemm0(const float* __restrict__ x, const float* __restrict__ W0,
                        const float* __restrict__ al, const float* __restrict__ ar,
                        float* __restrict__ f0, float* __restrict__ el,
                        float* __restrict__ er, int N) {
  int col = threadIdx.x;            // 0..255 == h*32+d
  int row0 = blockIdx.x * 8;
  const float* xr[8];
#pragma unroll
  for (int r = 0; r < 8; ++r) {
    int row = row0 + r; if (row >= N) row = N - 1;
    xr[r] = x + (size_t)row * 128;  // wave-uniform -> scalar loads
  }
  float acc[4][8];
#pragma unroll
  for (int c = 0; c < 4; ++c)
#pragma unroll
    for (int r = 0; r < 8; ++r) acc[c][r] = 0.f;

#pragma unroll
  for (int c = 0; c < 4; ++c) {
    const float* Wc = W0 + (size_t)(c * 32) * 256 + col;
#pragma unroll 4
    for (int kk = 0; kk < 32; ++kk) {
      float w = Wc[kk * 256];
      int k = c * 32 + kk;
#pragma unroll
      for (int r = 0; r < 8; ++r) acc[c][r] = fmaf(xr[r][k], w, acc[c][r]);
    }
  }

  int h = col >> 5;
  float a_l = al[col], a_r = ar[col];
#pragma unroll
  for (int r = 0; r < 8; ++r) {
    int row = row0 + r;
    float f = (acc[0][r] + acc[1][r]) + (acc[2][r] + acc[3][r]);
    if (row < N) f0[(size_t)row * 256 + col] = f;
    float pl = f * a_l;
    float pr = f * a_r;
#pragma unroll
    for (int off = 16; off >= 1; off >>= 1) {
      pl += __shfl_xor(pl, off, 32);
      pr += __shfl_xor(pr, off, 32);
    }
    if ((col & 31) == 0 && row < N) {
      el[row * 8 + h] = pl;
      er[row * 8 + h] = pr;
    }
  }
}

// ---------------- fused edge kernel layer 0 ----------------
// one block = one dst node; 256 thr = (h = t>>5, lane = t&31)
// score -> segment softmax (LDS) -> weighted gather-sum of f0 -> +b0 -> ELU
__global__ void k_fused0(const float* __restrict__ el, const float* __restrict__ er,
                         const float* __restrict__ f0, const int* __restrict__ indptr,
                         const int* __restrict__ ecsr, const int* __restrict__ src,
                         const float* __restrict__ b0, float* __restrict__ hout, int N) {
  __shared__ float s_w[CAP0 * 8];
  __shared__ int s_src[CAP0];
  int n = blockIdx.x;
  int t = threadIdx.x;
  int h = t >> 5, lane = t & 31;
  int s = indptr[n], e_ = indptr[n + 1];
  int deg = e_ - s;
  float er_h = er[n * 8 + h];
  float acc = 0.f;
  if (deg <= CAP0) {
    float m = -INFINITY;
    for (int i = lane; i < deg; i += 32) {
      int e = ecsr[s + i];
      int sn = src[e];
      if (h == 0) s_src[i] = sn;
      float v = el[sn * 8 + h] + er_h;
      v = v >= 0.f ? v : 0.2f * v;
      s_w[i * 8 + h] = v;
      m = fmaxf(m, v);
    }
#pragma unroll
    for (int off = 16; off >= 1; off >>= 1) m = fmaxf(m, __shfl_xor(m, off, 32));
    float sum = 0.f;
    for (int i = lane; i < deg; i += 32) {
      float a = expf(s_w[i * 8 + h] - m);
      s_w[i * 8 + h] = a;
      sum += a;
    }
#pragma unroll
    for (int off = 16; off >= 1; off >>= 1) sum += __shfl_xor(sum, off, 32);
    for (int i = lane; i < deg; i += 32) s_w[i * 8 + h] /= sum;   // IEEE div as reference
    __syncthreads();
    int i = 0;
    for (; i + 4 <= deg; i += 4) {
      float a0 = s_w[(i + 0) * 8 + h], a1 = s_w[(i + 1) * 8 + h];
      float a2 = s_w[(i + 2) * 8 + h], a3 = s_w[(i + 3) * 8 + h];
      int n0 = s_src[i + 0], n1 = s_src[i + 1], n2 = s_src[i + 2], n3 = s_src[i + 3];
      float v0 = f0[(size_t)n0 * 256 + t];
      float v1 = f0[(size_t)n1 * 256 + t];
      float v2 = f0[(size_t)n2 * 256 + t];
      float v3 = f0[(size_t)n3 * 256 + t];
      acc += a0 * v0; acc += a1 * v1; acc += a2 * v2; acc += a3 * v3;
    }
    for (; i < deg; ++i) acc += s_w[i * 8 + h] * f0[(size_t)s_src[i] * 256 + t];
  } else {
    // 3-pass recompute fallback (no LDS capacity) — block-uniform branch
    float m = -INFINITY;
    for (int i = lane; i < deg; i += 32) {
      float v = el[src[ecsr[s + i]] * 8 + h] + er_h;
      v = v >= 0.f ? v : 0.2f * v;
      m = fmaxf(m, v);
    }
#pragma unroll
    for (int off = 16; off >= 1; off >>= 1) m = fmaxf(m, __shfl_xor(m, off, 32));
    float sum = 0.f;
    for (int i = lane; i < deg; i += 32) {
      float v = el[src[ecsr[s + i]] * 8 + h] + er_h;
      v = v >= 0.f ? v : 0.2f * v;
      sum += expf(v - m);
    }
#pragma unroll
    for (int off = 16; off >= 1; off >>= 1) sum += __shfl_xor(sum, off, 32);
    for (int i = 0; i < deg; ++i) {
      int sn = src[ecsr[s + i]];
      float v = el[sn * 8 + h] + er_h;
      v = v >= 0.f ? v : 0.2f * v;
      float a = expf(v - m) / sum;
      acc += a * f0[(size_t)sn * 256 + t];
    }
  }
  float o = acc + b0[t];
  hout[(size_t)n * 256 + t] = o > 0.f ? o : expm1f(o);   // jax.nn.elu
}

// ---------------- GEMM1 + fused attention dots (layer 1, H=1) ----------------
// f1[N,32] = h[N,256] @ W1[256,32], fp32 2-chunk acc, float4 h loads
__global__ void k_gemm1(const float* __restrict__ h, const float* __restrict__ W1,
                        const float* __restrict__ al, const float* __restrict__ ar,
                        float* __restrict__ f1, float* __restrict__ el,
                        float* __restrict__ er, int N) {
  int t = threadIdx.x;
  int r = t >> 5, col = t & 31;
  int row = blockIdx.x * 8 + r;
  int rr = row < N ? row : N - 1;
  const float* hr = h + (size_t)rr * 256;
  float c0 = 0.f, c1 = 0.f;
#pragma unroll 4
  for (int k4 = 0; k4 < 32; ++k4) {
    float4 hv = *(const float4*)(hr + k4 * 4);
    const float* wp = W1 + (size_t)(k4 * 4) * 32 + col;
    c0 = fmaf(hv.x, wp[0],  c0);
    c0 = fmaf(hv.y, wp[32], c0);
    c0 = fmaf(hv.z, wp[64], c0);
    c0 = fmaf(hv.w, wp[96], c0);
  }
#pragma unroll 4
  for (int k4 = 32; k4 < 64; ++k4) {
    float4 hv = *(const float4*)(hr + k4 * 4);
    const float* wp = W1 + (size_t)(k4 * 4) * 32 + col;
    c1 = fmaf(hv.x, wp[0],  c1);
    c1 = fmaf(hv.y, wp[32], c1);
    c1 = fmaf(hv.z, wp[64], c1);
    c1 = fmaf(hv.w, wp[96], c1);
  }
  float f = c0 + c1;
  float pl = f * al[col];
  float pr = f * ar[col];
#pragma unroll
  for (int off = 16; off >= 1; off >>= 1) {
    pl += __shfl_xor(pl, off, 32);
    pr += __shfl_xor(pr, off, 32);
  }
  if (row < N) {
    f1[(size_t)row * 32 + col] = f;
    if (col == 0) { el[row] = pl; er[row] = pr; }
  }
}

// ---------------- fused edge kernel layer 1 (H=1, D=32) ----------------
// block = 256 = 4 nodes x 64 lanes (one wave per node)
__global__ void k_fused1(const float* __restrict__ el, const float* __restrict__ er,
                         const float* __restrict__ f1, const int* __restrict__ indptr,
                         const int* __restrict__ ecsr, const int* __restrict__ src,
                         const float* __restrict__ b1, float* __restrict__ h1, int N) {
  __shared__ float s_w[4][CAP0];
  __shared__ int s_s[4][CAP0];
  int g = threadIdx.x >> 6;
  int lane = threadIdx.x & 63;
  int n = blockIdx.x * 4 + g;
  int nn = n < N ? n : N - 1;
  int s = indptr[nn], e_ = indptr[nn + 1];
  int deg = e_ - s;
  float er_n = er[nn];
  float acc = 0.f;
  int d = lane & 31;
  if (deg <= CAP0) {
    float m = -INFINITY;
    for (int i = lane; i < deg; i += 64) {
      int e = ecsr[s + i];
      int sn = src[e];
      s_s[g][i] = sn;
      float v = el[sn] + er_n;
      v = v >= 0.f ? v : 0.2f * v;
      s_w[g][i] = v;
      m = fmaxf(m, v);
    }
#pragma unroll
    for (int off = 32; off >= 1; off >>= 1) m = fmaxf(m, __shfl_xor(m, off, 64));
    float sum = 0.f;
    for (int i = lane; i < deg; i += 64) {
      float a = expf(s_w[g][i] - m);
      s_w[g][i] = a;
      sum += a;
    }
#pragma unroll
    for (int off = 32; off >= 1; off >>= 1) sum += __shfl_xor(sum, off, 64);
    for (int i = lane; i < deg; i += 64) s_w[g][i] /= sum;
    if (lane < 32) {
      int i = 0;
      for (; i + 4 <= deg; i += 4) {
        float a0 = s_w[g][i + 0], a1 = s_w[g][i + 1], a2 = s_w[g][i + 2], a3 = s_w[g][i + 3];
        int n0 = s_s[g][i + 0], n1 = s_s[g][i + 1], n2 = s_s[g][i + 2], n3 = s_s[g][i + 3];
        float v0 = f1[(size_t)n0 * 32 + d];
        float v1 = f1[(size_t)n1 * 32 + d];
        float v2 = f1[(size_t)n2 * 32 + d];
        float v3 = f1[(size_t)n3 * 32 + d];
        acc += a0 * v0; acc += a1 * v1; acc += a2 * v2; acc += a3 * v3;
      }
      for (; i < deg; ++i) acc += s_w[g][i] * f1[(size_t)s_s[g][i] * 32 + d];
    }
  } else {
    float m = -INFINITY;
    for (int i = lane; i < deg; i += 64) {
      float v = el[src[ecsr[s + i]]] + er_n;
      v = v >= 0.f ? v : 0.2f * v;
      m = fmaxf(m, v);
    }
#pragma unroll
    for (int off = 32; off >= 1; off >>= 1) m = fmaxf(m, __shfl_xor(m, off, 64));
    float sum = 0.f;
    for (int i = lane; i < deg; i += 64) {
      float v = el[src[ecsr[s + i]]] + er_n;
      v = v >= 0.f ? v : 0.2f * v;
      sum += expf(v - m);
    }
#pragma unroll
    for (int off = 32; off >= 1; off >>= 1) sum += __shfl_xor(sum, off, 64);
    if (lane < 32) {
      for (int i = 0; i < deg; ++i) {
        int sn = src[ecsr[s + i]];
        float v = el[sn] + er_n;
        v = v >= 0.f ? v : 0.2f * v;
        float a = expf(v - m) / sum;
        acc += a * f1[(size_t)sn * 32 + d];
      }
    }
  }
  if (lane < 32 && n < N) h1[(size_t)n * 32 + d] = acc + b1[d];
}

// ---------------- predictor (f64 acc — negligible cost, keeps margin) ----------------
__global__ void k_pred(const float* __restrict__ h1, const float* __restrict__ P1,
                       const float* __restrict__ pb1, const float* __restrict__ P2,
                       const float* __restrict__ pb2, const float* __restrict__ P3,
                       const float* __restrict__ pb3, float* __restrict__ out,
                       int num_edge, int total) {
  int t = threadIdx.x;
  int lane = t & 31, grp = t >> 5;
  int k = blockIdx.x * 8 + grp;
  int kk = k < total ? k : 0;
  float z;
  if (kk < num_edge) {
    z = h1[(size_t)kk * 32 + lane] * h1[(size_t)(kk + num_edge) * 32 + lane];
  } else {
    int i = kk - num_edge;
    z = h1[(size_t)(i % num_edge) * 32 + lane] * h1[(size_t)(2 * num_edge + i) * 32 + lane];
  }
  double a1 = 0;
#pragma unroll
  for (int d = 0; d < 32; ++d)
    a1 += (double)__shfl(z, d, 32) * (double)P1[d * 32 + lane];
  float t1 = (float)(a1 + (double)pb1[lane]);
  t1 = t1 > 0.f ? t1 : 0.f;
  double a2 = 0;
#pragma unroll
  for (int d = 0; d < 32; ++d)
    a2 += (double)__shfl(t1, d, 32) * (double)P2[d * 32 + lane];
  float t2 = (float)(a2 + (double)pb2[lane]);
  t2 = t2 > 0.f ? t2 : 0.f;
  double a3 = (double)t2 * (double)P3[lane];
#pragma unroll
  for (int off = 16; off >= 1; off >>= 1) a3 += __shfl_xor(a3, off, 64);
  if (lane == 0 && k < total) out[k] = (float)(a3 + (double)pb3[0]);
}

extern "C" void kernel_launch(void* const* d_in, const int* in_sizes, int n_in,
                              void* d_out, int out_size, void* d_ws, size_t ws_size,
                              hipStream_t stream) {
  const float* x   = (const float*)d_in[0];
  const int*   src = (const int*)d_in[1];
  const int*   dst = (const int*)d_in[2];
  const float* W0  = (const float*)d_in[4];
  const float* al0 = (const float*)d_in[5];
  const float* ar0 = (const float*)d_in[6];
  const float* b0  = (const float*)d_in[7];
  const float* W1  = (const float*)d_in[8];
  const float* al1 = (const float*)d_in[9];
  const float* ar1 = (const float*)d_in[10];
  const float* b1  = (const float*)d_in[11];
  const float* P1  = (const float*)d_in[12];
  const float* pb1 = (const float*)d_in[13];
  const float* P2  = (const float*)d_in[14];
  const float* pb2 = (const float*)d_in[15];
  const float* P3  = (const float*)d_in[16];
  const float* pb3 = (const float*)d_in[17];

  int N = in_sizes[0] / 128;
  int E = in_sizes[1];
  int num_edge = N - out_size;   // N=(2+r)*ne, out=(1+r)*ne

  size_t off = 0;
  auto alloc = [&](size_t bytes) -> void* {
    void* p = (char*)d_ws + off;
    off += (bytes + 255) & ~(size_t)255;
    return p;
  };
  float* f0     = (float*)alloc((size_t)N * 256 * 4);
  float* hbuf   = (float*)alloc((size_t)N * 256 * 4);
  float* el     = (float*)alloc((size_t)N * 8 * 4);
  float* er     = (float*)alloc((size_t)N * 8 * 4);
  int*   indptr = (int*)alloc((size_t)(N + 1) * 4);
  int*   ecsr   = (int*)alloc((size_t)E * 4);
  int*   counts = (int*)alloc((size_t)N * 4);
  int*   cursor = (int*)alloc((size_t)N * 4);
  int*   partial= (int*)alloc((size_t)N * 4);
  int*   bsums  = (int*)alloc(256 * 4);
  if (off > ws_size) return;
  // aliases (disjoint lifetimes)
  float* f1  = f0;                   // f0 dead after k_fused0
  float* h1  = f0 + (size_t)N * 32;
  float* el1 = el;                   // layer0 el/er dead after k_fused0
  float* er1 = er;

  int gE = (E + 255) / 256;
  int gN = (N + 255) / 256;          // 196 blocks
  hipMemsetAsync(counts, 0, (size_t)N * 4, stream);
  hipMemsetAsync(cursor, 0, (size_t)N * 4, stream);
  k_hist<<<gE, 256, 0, stream>>>(dst, counts, E);
  k_blockscan<<<gN, 256, 0, stream>>>(counts, partial, bsums, N);
  k_scansums<<<1, 256, 0, stream>>>(bsums, gN);
  k_addoff<<<gN, 256, 0, stream>>>(partial, bsums, indptr, N);
  k_scatter<<<gE, 256, 0, stream>>>(dst, indptr, cursor, ecsr, E);
  k_sortbuckets<<<gN, 256, 0, stream>>>(indptr, ecsr, N);

  k_gemm0<<<(N + 7) / 8, 256, 0, stream>>>(x, W0, al0, ar0, f0, el, er, N);
  k_fused0<<<N, 256, 0, stream>>>(el, er, f0, indptr, ecsr, src, b0, hbuf, N);

  k_gemm1<<<(N + 7) / 8, 256, 0, stream>>>(hbuf, W1, al1, ar1, f1, el1, er1, N);
  k_fused1<<<(N + 3) / 4, 256, 0, stream>>>(el1, er1, f1, indptr, ecsr, src, b1, h1, N);

  k_pred<<<(out_size + 7) / 8, 256, 0, stream>>>(h1, P1, pb1, P2, pb2, P3, pb3,
                                                 (float*)d_out, num_edge, out_size);
}

// Round 4
// 560.883 us; speedup vs baseline: 1.9855x; 1.0715x over previous
//
#include <hip/hip_runtime.h>
#include <cmath>

#ifndef CAP0
#define CAP0 192   // max staged degree; Poisson(16) max ~45. Fallback path covers >CAP.
#endif

// ---------------- CSR build (by dst) ----------------
__global__ void k_hist(const int* __restrict__ dst, int* __restrict__ counts, int E) {
  int e = blockIdx.x * blockDim.x + threadIdx.x;
  if (e < E) atomicAdd(&counts[dst[e]], 1);
}

// inclusive scan within 256-blocks
__global__ void k_blockscan(const int* __restrict__ counts, int* __restrict__ partial,
                            int* __restrict__ bsums, int n) {
  __shared__ int buf[256];
  int tid = threadIdx.x;
  int i = blockIdx.x * 256 + tid;
  int v = (i < n) ? counts[i] : 0;
  buf[tid] = v;
  __syncthreads();
  for (int off = 1; off < 256; off <<= 1) {
    int t = (tid >= off) ? buf[tid - off] : 0;
    __syncthreads();
    buf[tid] += t;
    __syncthreads();
  }
  if (i < n) partial[i] = buf[tid];
  if (tid == 255) bsums[blockIdx.x] = buf[255];
}

// exclusive scan of block sums (nb <= 256), in place
__global__ void k_scansums(int* __restrict__ bsums, int nb) {
  __shared__ int buf[256];
  int tid = threadIdx.x;
  int v = (tid < nb) ? bsums[tid] : 0;
  buf[tid] = v;
  __syncthreads();
  for (int off = 1; off < 256; off <<= 1) {
    int t = (tid >= off) ? buf[tid - off] : 0;
    __syncthreads();
    buf[tid] += t;
    __syncthreads();
  }
  if (tid < nb) bsums[tid] = buf[tid] - v;
}

__global__ void k_addoff(const int* __restrict__ partial, const int* __restrict__ bsums,
                         int* __restrict__ indptr, int n) {
  int i = blockIdx.x * blockDim.x + threadIdx.x;
  if (i == 0) indptr[0] = 0;
  if (i < n) indptr[i + 1] = partial[i] + bsums[i >> 8];
}

// NOTE: bucket order = atomic completion order (nondeterministic). Aggregation
// reorder shifts fp32 sums by ~1 ulp of h (~1e-9 at final output) — accepted;
// the explicit insertion sort cost far more (deg^2 latency tail on one wave).
__global__ void k_scatter(const int* __restrict__ dst, const int* __restrict__ indptr,
                          int* __restrict__ cursor, int* __restrict__ ecsr, int E) {
  int e = blockIdx.x * blockDim.x + threadIdx.x;
  if (e < E) {
    int d = dst[e];
    int pos = indptr[d] + atomicAdd(&cursor[d], 1);
    ecsr[pos] = e;
  }
}

// ---------------- GEMM0 + fused attention dots (layer 0) ----------------
// f0[N,256] = x[N,128] @ W0[128,256], fp32 4-chunk blocked acc
__global__ void k_gemm0(const float* __restrict__ x, const float* __restrict__ W0,
                        const float* __restrict__ al, const float* __restrict__ ar,
                        float* __restrict__ f0, float* __restrict__ el,
                        float* __restrict__ er, int N) {
  int col = threadIdx.x;            // 0..255 == h*32+d
  int row0 = blockIdx.x * 8;
  const float* xr[8];
#pragma unroll
  for (int r = 0; r < 8; ++r) {
    int row = row0 + r; if (row >= N) row = N - 1;
    xr[r] = x + (size_t)row * 128;  // wave-uniform -> scalar loads
  }
  float acc[4][8];
#pragma unroll
  for (int c = 0; c < 4; ++c)
#pragma unroll
    for (int r = 0; r < 8; ++r) acc[c][r] = 0.f;

#pragma unroll
  for (int c = 0; c < 4; ++c) {
    const float* Wc = W0 + (size_t)(c * 32) * 256 + col;
#pragma unroll 4
    for (int kk = 0; kk < 32; ++kk) {
      float w = Wc[kk * 256];
      int k = c * 32 + kk;
#pragma unroll
      for (int r = 0; r < 8; ++r) acc[c][r] = fmaf(xr[r][k], w, acc[c][r]);
    }
  }

  int h = col >> 5;
  float a_l = al[col], a_r = ar[col];
#pragma unroll
  for (int r = 0; r < 8; ++r) {
    int row = row0 + r;
    float f = (acc[0][r] + acc[1][r]) + (acc[2][r] + acc[3][r]);
    if (row < N) f0[(size_t)row * 256 + col] = f;
    float pl = f * a_l;
    float pr = f * a_r;
#pragma unroll
    for (int off = 16; off >= 1; off >>= 1) {
      pl += __shfl_xor(pl, off, 32);
      pr += __shfl_xor(pr, off, 32);
    }
    if ((col & 31) == 0 && row < N) {
      el[row * 8 + h] = pl;
      er[row * 8 + h] = pr;
    }
  }
}

// ---------------- fused edge kernel layer 0 ----------------
// one block = one dst node; phase 1: scores+softmax (8 heads x 32 lanes);
// phase 2: wave-wide float4 gather — one wave covers all 256 dims of a row,
// 4 waves stride over edges, LDS reduce across waves.
__global__ void k_fused0(const float* __restrict__ el, const float* __restrict__ er,
                         const float* __restrict__ f0, const int* __restrict__ indptr,
                         const int* __restrict__ ecsr, const int* __restrict__ src,
                         const float* __restrict__ b0, float* __restrict__ hout, int N) {
  __shared__ float s_w[CAP0 * 8];
  __shared__ int s_src[CAP0];
  __shared__ float s_red[4][256];
  int n = blockIdx.x;
  int t = threadIdx.x;
  int h = t >> 5, lane = t & 31;
  int s = indptr[n], e_ = indptr[n + 1];
  int deg = e_ - s;
  float er_h = er[n * 8 + h];

  if (deg <= CAP0) {
    // ---- phase 1: scores + segment softmax into s_w ----
    float m = -INFINITY;
    for (int i = lane; i < deg; i += 32) {
      int e = ecsr[s + i];
      int sn = src[e];
      if (h == 0) s_src[i] = sn;
      float v = el[sn * 8 + h] + er_h;
      v = v >= 0.f ? v : 0.2f * v;
      s_w[i * 8 + h] = v;
      m = fmaxf(m, v);
    }
#pragma unroll
    for (int off = 16; off >= 1; off >>= 1) m = fmaxf(m, __shfl_xor(m, off, 32));
    float sum = 0.f;
    for (int i = lane; i < deg; i += 32) {
      float a = expf(s_w[i * 8 + h] - m);
      s_w[i * 8 + h] = a;
      sum += a;
    }
#pragma unroll
    for (int off = 16; off >= 1; off >>= 1) sum += __shfl_xor(sum, off, 32);
    for (int i = lane; i < deg; i += 32) s_w[i * 8 + h] /= sum;   // IEEE div as reference
    __syncthreads();

    // ---- phase 2: gather. wave w handles edges w, w+4, ... ----
    int w = t >> 6;
    int l = t & 63;                  // float4 slot: dims 4l..4l+3
    int hh = l >> 3;                 // head of this slot
    float4 a4 = make_float4(0.f, 0.f, 0.f, 0.f);
    int i = w;
    for (; i + 4 < deg; i += 8) {
      float a0 = s_w[i * 8 + hh];
      float a1 = s_w[(i + 4) * 8 + hh];
      float4 v0 = ((const float4*)(f0 + (size_t)s_src[i] * 256))[l];
      float4 v1 = ((const float4*)(f0 + (size_t)s_src[i + 4] * 256))[l];
      a4.x = fmaf(a0, v0.x, a4.x); a4.y = fmaf(a0, v0.y, a4.y);
      a4.z = fmaf(a0, v0.z, a4.z); a4.w = fmaf(a0, v0.w, a4.w);
      a4.x = fmaf(a1, v1.x, a4.x); a4.y = fmaf(a1, v1.y, a4.y);
      a4.z = fmaf(a1, v1.z, a4.z); a4.w = fmaf(a1, v1.w, a4.w);
    }
    if (i < deg) {
      float a0 = s_w[i * 8 + hh];
      float4 v0 = ((const float4*)(f0 + (size_t)s_src[i] * 256))[l];
      a4.x = fmaf(a0, v0.x, a4.x); a4.y = fmaf(a0, v0.y, a4.y);
      a4.z = fmaf(a0, v0.z, a4.z); a4.w = fmaf(a0, v0.w, a4.w);
    }
    ((float4*)s_red[w])[l] = a4;
    __syncthreads();
    float o = ((s_red[0][t] + s_red[1][t]) + (s_red[2][t] + s_red[3][t])) + b0[t];
    hout[(size_t)n * 256 + t] = o > 0.f ? o : expm1f(o);   // jax.nn.elu
  } else {
    // 3-pass recompute fallback — block-uniform branch
    float m = -INFINITY;
    for (int i = lane; i < deg; i += 32) {
      float v = el[src[ecsr[s + i]] * 8 + h] + er_h;
      v = v >= 0.f ? v : 0.2f * v;
      m = fmaxf(m, v);
    }
#pragma unroll
    for (int off = 16; off >= 1; off >>= 1) m = fmaxf(m, __shfl_xor(m, off, 32));
    float sum = 0.f;
    for (int i = lane; i < deg; i += 32) {
      float v = el[src[ecsr[s + i]] * 8 + h] + er_h;
      v = v >= 0.f ? v : 0.2f * v;
      sum += expf(v - m);
    }
#pragma unroll
    for (int off = 16; off >= 1; off >>= 1) sum += __shfl_xor(sum, off, 32);
    float acc = 0.f;
    for (int i = 0; i < deg; ++i) {
      int sn = src[ecsr[s + i]];
      float v = el[sn * 8 + h] + er_h;
      v = v >= 0.f ? v : 0.2f * v;
      float a = expf(v - m) / sum;
      acc += a * f0[(size_t)sn * 256 + t];
    }
    float o = acc + b0[t];
    hout[(size_t)n * 256 + t] = o > 0.f ? o : expm1f(o);
  }
}

// ---------------- GEMM1 + fused attention dots (layer 1, H=1) ----------------
__global__ void k_gemm1(const float* __restrict__ h, const float* __restrict__ W1,
                        const float* __restrict__ al, const float* __restrict__ ar,
                        float* __restrict__ f1, float* __restrict__ el,
                        float* __restrict__ er, int N) {
  int t = threadIdx.x;
  int r = t >> 5, col = t & 31;
  int row = blockIdx.x * 8 + r;
  int rr = row < N ? row : N - 1;
  const float* hr = h + (size_t)rr * 256;
  float c0 = 0.f, c1 = 0.f;
#pragma unroll 4
  for (int k4 = 0; k4 < 32; ++k4) {
    float4 hv = *(const float4*)(hr + k4 * 4);
    const float* wp = W1 + (size_t)(k4 * 4) * 32 + col;
    c0 = fmaf(hv.x, wp[0],  c0);
    c0 = fmaf(hv.y, wp[32], c0);
    c0 = fmaf(hv.z, wp[64], c0);
    c0 = fmaf(hv.w, wp[96], c0);
  }
#pragma unroll 4
  for (int k4 = 32; k4 < 64; ++k4) {
    float4 hv = *(const float4*)(hr + k4 * 4);
    const float* wp = W1 + (size_t)(k4 * 4) * 32 + col;
    c1 = fmaf(hv.x, wp[0],  c1);
    c1 = fmaf(hv.y, wp[32], c1);
    c1 = fmaf(hv.z, wp[64], c1);
    c1 = fmaf(hv.w, wp[96], c1);
  }
  float f = c0 + c1;
  float pl = f * al[col];
  float pr = f * ar[col];
#pragma unroll
  for (int off = 16; off >= 1; off >>= 1) {
    pl += __shfl_xor(pl, off, 32);
    pr += __shfl_xor(pr, off, 32);
  }
  if (row < N) {
    f1[(size_t)row * 32 + col] = f;
    if (col == 0) { el[row] = pl; er[row] = pr; }
  }
}

// ---------------- fused edge kernel layer 1 (H=1, D=32) ----------------
// block = 4 nodes x 64 lanes. agg: 8 edge-slots x 8 lanes x float4 (= one
// 128 B row per 8-lane group), shuffle-reduce across slots.
__global__ void k_fused1(const float* __restrict__ el, const float* __restrict__ er,
                         const float* __restrict__ f1, const int* __restrict__ indptr,
                         const int* __restrict__ ecsr, const int* __restrict__ src,
                         const float* __restrict__ b1, float* __restrict__ h1, int N) {
  __shared__ float s_w[4][CAP0];
  __shared__ int s_s[4][CAP0];
  int g = threadIdx.x >> 6;
  int lane = threadIdx.x & 63;
  int n = blockIdx.x * 4 + g;
  int nn = n < N ? n : N - 1;
  int s = indptr[nn], e_ = indptr[nn + 1];
  int deg = e_ - s;
  float er_n = er[nn];
  if (deg <= CAP0) {
    float m = -INFINITY;
    for (int i = lane; i < deg; i += 64) {
      int e = ecsr[s + i];
      int sn = src[e];
      s_s[g][i] = sn;
      float v = el[sn] + er_n;
      v = v >= 0.f ? v : 0.2f * v;
      s_w[g][i] = v;
      m = fmaxf(m, v);
    }
#pragma unroll
    for (int off = 32; off >= 1; off >>= 1) m = fmaxf(m, __shfl_xor(m, off, 64));
    float sum = 0.f;
    for (int i = lane; i < deg; i += 64) {
      float a = expf(s_w[g][i] - m);
      s_w[g][i] = a;
      sum += a;
    }
#pragma unroll
    for (int off = 32; off >= 1; off >>= 1) sum += __shfl_xor(sum, off, 64);
    for (int i = lane; i < deg; i += 64) s_w[g][i] /= sum;
    // agg: slot es = lane>>3 handles edges es, es+8, ...; q = lane&7 -> dims 4q..4q+3
    int es = lane >> 3, q = lane & 7;
    float4 a4 = make_float4(0.f, 0.f, 0.f, 0.f);
    for (int i = es; i < deg; i += 8) {
      float a = s_w[g][i];
      float4 v = ((const float4*)(f1 + (size_t)s_s[g][i] * 32))[q];
      a4.x = fmaf(a, v.x, a4.x); a4.y = fmaf(a, v.y, a4.y);
      a4.z = fmaf(a, v.z, a4.z); a4.w = fmaf(a, v.w, a4.w);
    }
#pragma unroll
    for (int off = 8; off <= 32; off <<= 1) {
      a4.x += __shfl_xor(a4.x, off, 64);
      a4.y += __shfl_xor(a4.y, off, 64);
      a4.z += __shfl_xor(a4.z, off, 64);
      a4.w += __shfl_xor(a4.w, off, 64);
    }
    if (lane < 8 && n < N) {
      float4 b = *(const float4*)(b1 + lane * 4);
      a4.x += b.x; a4.y += b.y; a4.z += b.z; a4.w += b.w;
      ((float4*)(h1 + (size_t)n * 32))[lane] = a4;
    }
  } else {
    float m = -INFINITY;
    for (int i = lane; i < deg; i += 64) {
      float v = el[src[ecsr[s + i]]] + er_n;
      v = v >= 0.f ? v : 0.2f * v;
      m = fmaxf(m, v);
    }
#pragma unroll
    for (int off = 32; off >= 1; off >>= 1) m = fmaxf(m, __shfl_xor(m, off, 64));
    float sum = 0.f;
    for (int i = lane; i < deg; i += 64) {
      float v = el[src[ecsr[s + i]]] + er_n;
      v = v >= 0.f ? v : 0.2f * v;
      sum += expf(v - m);
    }
#pragma unroll
    for (int off = 32; off >= 1; off >>= 1) sum += __shfl_xor(sum, off, 64);
    int d = lane & 31;
    float acc = 0.f;
    if (lane < 32) {
      for (int i = 0; i < deg; ++i) {
        int sn = src[ecsr[s + i]];
        float v = el[sn] + er_n;
        v = v >= 0.f ? v : 0.2f * v;
        float a = expf(v - m) / sum;
        acc = fmaf(a, f1[(size_t)sn * 32 + d], acc);
      }
      if (n < N) h1[(size_t)n * 32 + d] = acc + b1[d];
    }
  }
}

// ---------------- predictor (f64 acc — negligible cost, keeps margin) ----------------
__global__ void k_pred(const float* __restrict__ h1, const float* __restrict__ P1,
                       const float* __restrict__ pb1, const float* __restrict__ P2,
                       const float* __restrict__ pb2, const float* __restrict__ P3,
                       const float* __restrict__ pb3, float* __restrict__ out,
                       int num_edge, int total) {
  int t = threadIdx.x;
  int lane = t & 31, grp = t >> 5;
  int k = blockIdx.x * 8 + grp;
  int kk = k < total ? k : 0;
  float z;
  if (kk < num_edge) {
    z = h1[(size_t)kk * 32 + lane] * h1[(size_t)(kk + num_edge) * 32 + lane];
  } else {
    int i = kk - num_edge;
    z = h1[(size_t)(i % num_edge) * 32 + lane] * h1[(size_t)(2 * num_edge + i) * 32 + lane];
  }
  double a1 = 0;
#pragma unroll
  for (int d = 0; d < 32; ++d)
    a1 += (double)__shfl(z, d, 32) * (double)P1[d * 32 + lane];
  float t1 = (float)(a1 + (double)pb1[lane]);
  t1 = t1 > 0.f ? t1 : 0.f;
  double a2 = 0;
#pragma unroll
  for (int d = 0; d < 32; ++d)
    a2 += (double)__shfl(t1, d, 32) * (double)P2[d * 32 + lane];
  float t2 = (float)(a2 + (double)pb2[lane]);
  t2 = t2 > 0.f ? t2 : 0.f;
  double a3 = (double)t2 * (double)P3[lane];
#pragma unroll
  for (int off = 16; off >= 1; off >>= 1) a3 += __shfl_xor(a3, off, 64);
  if (lane == 0 && k < total) out[k] = (float)(a3 + (double)pb3[0]);
}

extern "C" void kernel_launch(void* const* d_in, const int* in_sizes, int n_in,
                              void* d_out, int out_size, void* d_ws, size_t ws_size,
                              hipStream_t stream) {
  const float* x   = (const float*)d_in[0];
  const int*   src = (const int*)d_in[1];
  const int*   dst = (const int*)d_in[2];
  const float* W0  = (const float*)d_in[4];
  const float* al0 = (const float*)d_in[5];
  const float* ar0 = (const float*)d_in[6];
  const float* b0  = (const float*)d_in[7];
  const float* W1  = (const float*)d_in[8];
  const float* al1 = (const float*)d_in[9];
  const float* ar1 = (const float*)d_in[10];
  const float* b1  = (const float*)d_in[11];
  const float* P1  = (const float*)d_in[12];
  const float* pb1 = (const float*)d_in[13];
  const float* P2  = (const float*)d_in[14];
  const float* pb2 = (const float*)d_in[15];
  const float* P3  = (const float*)d_in[16];
  const float* pb3 = (const float*)d_in[17];

  int N = in_sizes[0] / 128;
  int E = in_sizes[1];
  int num_edge = N - out_size;   // N=(2+r)*ne, out=(1+r)*ne

  size_t off = 0;
  auto alloc = [&](size_t bytes) -> void* {
    void* p = (char*)d_ws + off;
    off += (bytes + 255) & ~(size_t)255;
    return p;
  };
  float* f0     = (float*)alloc((size_t)N * 256 * 4);
  float* hbuf   = (float*)alloc((size_t)N * 256 * 4);
  float* el     = (float*)alloc((size_t)N * 8 * 4);
  float* er     = (float*)alloc((size_t)N * 8 * 4);
  int*   indptr = (int*)alloc((size_t)(N + 1) * 4);
  int*   ecsr   = (int*)alloc((size_t)E * 4);
  int*   counts = (int*)alloc((size_t)N * 4);
  int*   cursor = (int*)alloc((size_t)N * 4);
  int*   partial= (int*)alloc((size_t)N * 4);
  int*   bsums  = (int*)alloc(256 * 4);
  if (off > ws_size) return;
  // aliases (disjoint lifetimes)
  float* f1  = f0;                   // f0 dead after k_fused0
  float* h1  = f0 + (size_t)N * 32;
  float* el1 = el;                   // layer0 el/er dead after k_fused0
  float* er1 = er;

  int gE = (E + 255) / 256;
  int gN = (N + 255) / 256;          // 196 blocks
  hipMemsetAsync(counts, 0, (size_t)N * 4, stream);
  hipMemsetAsync(cursor, 0, (size_t)N * 4, stream);
  k_hist<<<gE, 256, 0, stream>>>(dst, counts, E);
  k_blockscan<<<gN, 256, 0, stream>>>(counts, partial, bsums, N);
  k_scansums<<<1, 256, 0, stream>>>(bsums, gN);
  k_addoff<<<gN, 256, 0, stream>>>(partial, bsums, indptr, N);
  k_scatter<<<gE, 256, 0, stream>>>(dst, indptr, cursor, ecsr, E);

  k_gemm0<<<(N + 7) / 8, 256, 0, stream>>>(x, W0, al0, ar0, f0, el, er, N);
  k_fused0<<<N, 256, 0, stream>>>(el, er, f0, indptr, ecsr, src, b0, hbuf, N);

  k_gemm1<<<(N + 7) / 8, 256, 0, stream>>>(hbuf, W1, al1, ar1, f1, el1, er1, N);
  k_fused1<<<(N + 3) / 4, 256, 0, stream>>>(el1, er1, f1, indptr, ecsr, src, b1, h1, N);

  k_pred<<<(out_size + 7) / 8, 256, 0, stream>>>(h1, P1, pb1, P2, pb2, P3, pb3,
                                                 (float*)d_out, num_edge, out_size);
}